// Round 2
// baseline (2164.686 us; speedup 1.0000x reference)
//
#include <hip/hip_runtime.h>
#include <hip/hip_fp16.h>
#include <math.h>

// SO3 DiT layer, MI355X fp32. N=6000, E=72000, P=2, L=2, M=9, F=64, H=4, DH=16
// R2: the R0/R1 edge kernels streamed fe (166 MB) through the SCALAR path
// (s_load broadcast GEMM) which ceilings at ~0.6 TB/s device-wide — that was
// the real limiter (removing 300 MB of atomic writes in R1 made it SLOWER).
// Now: all broadcast operands go through the VECTOR path (64 lanes load the
// same float4 -> one L1 request), forced by an opaque VGPR zero (vzero) so the
// compiler can't re-scalarize. eq/ev are never materialized: k_flogits fuses
// the eq-GEMM with the qk dot; k_fagg fuses the ev-GEMM with the CSR-gather
// aggregation (block per dst, register accumulate, LDS reduce, write once).
// q/k/v are fp16 intermediates (halves gather traffic; logits accumulate fp32).

#define NN 6000
#define EE 72000

__device__ __forceinline__ float wsum(float v) {
#pragma unroll
  for (int o = 32; o >= 1; o >>= 1) v += __shfl_xor(v, o, 64);
  return v;
}
__device__ __forceinline__ int deg_of(int m) { return (m == 0) ? 0 : ((m < 4) ? 1 : 2); }
// order-preserving float->uint for atomicMax-based segment max
__device__ __forceinline__ unsigned fenc(float x) {
  unsigned u = __float_as_uint(x);
  return (u & 0x80000000u) ? ~u : (u | 0x80000000u);
}
__device__ __forceinline__ float fdec(unsigned k) {
  unsigned u = (k & 0x80000000u) ? (k & 0x7fffffffu) : ~k;
  return __uint_as_float(u);
}
// opaque zero in a VGPR: forces derived addresses onto the vector-memory path
__device__ __forceinline__ int vzero() {
  int z;
  asm volatile("v_mov_b32 %0, 0" : "=v"(z));
  return z;
}

// ---------------- K1a: LayerNorm(T=64) + SiLU, one wave per node ----------------
__global__ __launch_bounds__(256) void k_ln_t(const float* __restrict__ ft,
                                              const float* __restrict__ lns,
                                              const float* __restrict__ lnb,
                                              float* __restrict__ sbuf) {
  int w = (blockIdx.x * 256 + threadIdx.x) >> 6;  // node, exact 6000
  int lane = threadIdx.x & 63;
  float t = ft[(size_t)w * 64 + lane];
  float mu = wsum(t) * (1.f / 64.f);
  float d = t - mu;
  float var = wsum(d * d) * (1.f / 64.f);
  float cin = d * rsqrtf(var + 1e-6f) * lns[lane] + lnb[lane];
  sbuf[(size_t)w * 64 + lane] = cin / (1.f + expf(-cin));
}

// ---------------- K1b: c = silu @ W_c + b_c  (64 -> 1664), 8 nodes/block ----------------
__global__ __launch_bounds__(256) void k_cond_mm(const float* __restrict__ sbuf,
                                                 const float* __restrict__ Wc,
                                                 const float* __restrict__ bc,
                                                 float* __restrict__ c) {
  int n0 = blockIdx.x * 8;  // 750 blocks
  int vz = vzero();
  for (int jj = threadIdx.x; jj < 1664; jj += 256) {
    float acc[8] = {0, 0, 0, 0, 0, 0, 0, 0};
#pragma unroll 8
    for (int k2 = 0; k2 < 64; k2++) {
      float wv = Wc[(size_t)k2 * 1664 + jj];
#pragma unroll
      for (int nd = 0; nd < 8; nd++)
        acc[nd] += sbuf[(size_t)(n0 + nd) * 64 + k2 + vz] * wv;
    }
    float b = bc[jj];
#pragma unroll
    for (int nd = 0; nd < 8; nd++) c[(size_t)(n0 + nd) * 1664 + jj] = acc[nd] + b;
  }
}

// ---------------- K2/K8: eqv layernorm + modulate, one wave per (n,p) ----------------
__global__ __launch_bounds__(256) void k_lnmod(const float* __restrict__ xin,
                                               const float* __restrict__ c,
                                               float* __restrict__ xout,
                                               int goff, int boff) {
  int w = (blockIdx.x * 256 + threadIdx.x) >> 6;  // (n,p) pair, exact 12000
  int lane = threadIdx.x & 63;
  int n = w >> 1, p = w & 1;
  const float* xb = xin + (size_t)w * 576 + lane;
  float x0 = xb[0], x1 = xb[64], x2 = xb[128], x3 = xb[192], x4 = xb[256];
  float x5 = xb[320], x6 = xb[384], x7 = xb[448], x8 = xb[512];
  float mu = wsum(x0) * (1.f / 64.f);
  x0 -= mu;
  float n20 = x0 * x0;
  float n21 = (x1 * x1 + x2 * x2 + x3 * x3) * (1.f / 3.f);
  float n22 = (x4 * x4 + x5 * x5 + x6 * x6 + x7 * x7 + x8 * x8) * (1.f / 5.f);
  n20 = wsum(n20) * (1.f / 64.f);
  n21 = wsum(n21) * (1.f / 64.f);
  n22 = wsum(n22) * (1.f / 64.f);
  float i0 = rsqrtf(n20 + 1e-6f), i1 = rsqrtf(n21 + 1e-6f), i2 = rsqrtf(n22 + 1e-6f);
  const float* cb = c + (size_t)n * 1664;
  float g0 = 1.f + cb[goff + p * 192 + lane];
  float g1 = 1.f + cb[goff + p * 192 + 64 + lane];
  float g2 = 1.f + cb[goff + p * 192 + 128 + lane];
  float bsh = cb[boff + lane];
  float* ob = xout + (size_t)w * 576 + lane;
  ob[0] = x0 * i0 * g0 + bsh;
  ob[64] = x1 * i1 * g1;
  ob[128] = x2 * i1 * g1;
  ob[192] = x3 * i1 * g1;
  ob[256] = x4 * i2 * g2;
  ob[320] = x5 * i2 * g2;
  ob[384] = x6 * i2 * g2;
  ob[448] = x7 * i2 * g2;
  ob[512] = x8 * i2 * g2;
}

// ---------------- CSR build: count, scan, fill ----------------
__global__ __launch_bounds__(256) void k_count(const int* __restrict__ dst_idx,
                                               const float* __restrict__ cutoff,
                                               float* __restrict__ cnt,
                                               float* __restrict__ cutsum) {
  int e = blockIdx.x * 256 + threadIdx.x;
  if (e >= EE) return;
  int d = dst_idx[e];
  unsafeAtomicAdd(cnt + d, 1.f);
  unsafeAtomicAdd(cutsum + d, cutoff[e]);
}

__global__ __launch_bounds__(1024) void k_scan(const float* __restrict__ cnt,
                                               int* __restrict__ rowptr,
                                               int* __restrict__ fillc) {
  __shared__ int part[1024];
  int t = threadIdx.x;
  int base = t * 6;  // 1024*6 = 6144 >= 6000
  int lc[6];
  int s = 0;
#pragma unroll
  for (int i = 0; i < 6; i++) {
    int idx = base + i;
    int vv = (idx < NN) ? (int)(cnt[idx] + 0.5f) : 0;
    lc[i] = s;
    s += vv;
  }
  part[t] = s;
  __syncthreads();
  for (int o = 1; o < 1024; o <<= 1) {
    int vv = (t >= o) ? part[t - o] : 0;
    __syncthreads();
    part[t] += vv;
    __syncthreads();
  }
  int ex = (t == 0) ? 0 : part[t - 1];
#pragma unroll
  for (int i = 0; i < 6; i++) {
    int idx = base + i;
    if (idx < NN) {
      int p = ex + lc[i];
      rowptr[idx] = p;
      fillc[idx] = p;
    }
  }
  if (t == 1023) rowptr[NN] = part[1023];  // == EE
}

__global__ __launch_bounds__(256) void k_fill(const int* __restrict__ dst_idx,
                                              const int* __restrict__ src_idx,
                                              const float* __restrict__ cutoff,
                                              int* __restrict__ fillc,
                                              int* __restrict__ eids,
                                              int* __restrict__ dsts,
                                              int* __restrict__ srcs,
                                              float* __restrict__ cuts) {
  int e = blockIdx.x * 256 + threadIdx.x;
  if (e >= EE) return;
  int d = dst_idx[e];
  int pos = atomicAdd(fillc + d, 1);
  eids[pos] = e;
  dsts[pos] = d;
  srcs[pos] = src_idx[e];
  cuts[pos] = cutoff[e];
}

// ---------------- K3: fused q/k/v projection, fp16 out, vector-broadcast GEMM ----------
__global__ __launch_bounds__(192) void k_qkv(const float* __restrict__ xpre,
                                             const float* __restrict__ Wq,
                                             const float* __restrict__ Wk,
                                             const float* __restrict__ Wv,
                                             __half* __restrict__ qh,
                                             __half* __restrict__ kh,
                                             __half* __restrict__ vh) {
  int pm = blockIdx.y;
  int p = pm / 9, dm = deg_of(pm % 9);
  int mat = threadIdx.x >> 6;  // 0=q 1=k 2=v (wave-uniform)
  int g = threadIdx.x & 63;
  int n0 = blockIdx.x * 8;  // 750 blocks
  const float* Wsel = (mat == 0) ? Wq : ((mat == 1) ? Wk : Wv);
  const float* Wb = Wsel + (size_t)(p * 3 + dm) * 4096;
  __half* ob = (mat == 0) ? qh : ((mat == 1) ? kh : vh);
  float wreg[64];
#pragma unroll
  for (int f = 0; f < 64; f++) wreg[f] = Wb[f * 64 + g];
  int vz = vzero();
  const float* xb = xpre + ((size_t)n0 * 18 + pm) * 64 + vz;
  float acc[8] = {0, 0, 0, 0, 0, 0, 0, 0};
#pragma unroll
  for (int t = 0; t < 16; t++) {
#pragma unroll
    for (int nd = 0; nd < 8; nd++) {
      const float4 a4 = *(const float4*)(xb + (size_t)nd * 1152 + 4 * t);
      acc[nd] += a4.x * wreg[4 * t] + a4.y * wreg[4 * t + 1] + a4.z * wreg[4 * t + 2] +
                 a4.w * wreg[4 * t + 3];
    }
  }
#pragma unroll
  for (int nd = 0; nd < 8; nd++)
    ob[((size_t)(n0 + nd) * 18 + pm) * 64 + g] = __float2half(acc[nd]);
}

// ---------------- K4: fused eq-GEMM + qk-dot logits + segment max (slot order) -------
__global__ __launch_bounds__(256) void k_flogits(const float* __restrict__ fe,
                                                 const float* __restrict__ Weqk,
                                                 const __half* __restrict__ qh,
                                                 const __half* __restrict__ kh,
                                                 const int* __restrict__ eids,
                                                 const int* __restrict__ dsts,
                                                 const int* __restrict__ srcs,
                                                 float* __restrict__ logw,
                                                 unsigned* __restrict__ lmax) {
  int g = threadIdx.x & 63;
  float wreg[64];
#pragma unroll
  for (int f = 0; f < 64; f++) wreg[f] = Weqk[f * 64 + g];
  int vz = vzero();
  int w = (blockIdx.x * 256 + threadIdx.x) >> 6;  // 18000 waves x 4 slots = 72000
  for (int s = w * 4; s < w * 4 + 4; s++) {
    int e = eids[s];
    int dst = dsts[s];
    int src = srcs[s];
    const float* feb = fe + (size_t)e * 576 + vz;  // vector-broadcast path
    float eq[9];
#pragma unroll
    for (int m = 0; m < 9; m++) eq[m] = 0.f;
#pragma unroll
    for (int t = 0; t < 16; t++) {
#pragma unroll
      for (int m = 0; m < 9; m++) {
        const float4 a4 = *(const float4*)(feb + m * 64 + 4 * t);
        eq[m] += a4.x * wreg[4 * t] + a4.y * wreg[4 * t + 1] + a4.z * wreg[4 * t + 2] +
                 a4.w * wreg[4 * t + 3];
      }
    }
    const __half* qb = qh + (size_t)dst * 1152 + g;
    const __half* kb = kh + (size_t)src * 1152 + g;
    float lacc = 0.f;
#pragma unroll
    for (int m = 0; m < 9; m++) {
      float qk = __half2float(qb[m * 64]) * __half2float(kb[m * 64]) +
                 __half2float(qb[m * 64 + 576]) * __half2float(kb[m * 64 + 576]);
      lacc += eq[m] * qk;
    }
    lacc *= 0.05892556509887896f;  // 1/sqrt(P*M*DH)=1/sqrt(288)
    lacc += __shfl_xor(lacc, 8, 64);
    lacc += __shfl_xor(lacc, 4, 64);
    lacc += __shfl_xor(lacc, 2, 64);
    lacc += __shfl_xor(lacc, 1, 64);
    if ((g & 15) == 0) {
      int h = g >> 4;
      logw[(size_t)s * 4 + h] = lacc;
      atomicMax(lmax + (size_t)dst * 4 + h, fenc(lacc));
    }
  }
}

// ---------------- K5: w = exp(logit - lmax)*cutoff (slot order), denom sum ----------
__global__ __launch_bounds__(256) void k_expw2(float* __restrict__ logw,
                                               const unsigned* __restrict__ lmax,
                                               const int* __restrict__ dsts,
                                               const float* __restrict__ cuts,
                                               float* __restrict__ denom) {
  int t = blockIdx.x * 256 + threadIdx.x;  // exact E*4
  int s = t >> 2, h = t & 3;
  int dst = dsts[s];
  float wv = expf(logw[t] - fdec(lmax[(size_t)dst * 4 + h])) * cuts[s];
  logw[t] = wv;
  unsafeAtomicAdd(denom + (size_t)dst * 4 + h, wv);
}

// ---------------- K6: fused ev-GEMM + attn*v accumulate, block per dst ----------------
__global__ __launch_bounds__(256) void k_fagg(const float* __restrict__ fe,
                                              const float* __restrict__ Wev,
                                              const __half* __restrict__ vh,
                                              const int* __restrict__ eids,
                                              const int* __restrict__ srcs,
                                              const int* __restrict__ rowptr,
                                              const float* __restrict__ w_ws,
                                              const float* __restrict__ denom,
                                              float* __restrict__ attn_out) {
  __shared__ float red[4][1152];
  int dst = blockIdx.x;  // 6000 blocks
  int g = threadIdx.x & 63;
  int wid = threadIdx.x >> 6;
  float wreg[64];
#pragma unroll
  for (int f = 0; f < 64; f++) wreg[f] = Wev[f * 64 + g];
  int vz = vzero();
  int e0 = rowptr[dst], e1 = rowptr[dst + 1];
  float invd = 1.f / (denom[(size_t)dst * 4 + (g >> 4)] + 1e-9f);
  float acc[18];
#pragma unroll
  for (int i = 0; i < 18; i++) acc[i] = 0.f;
  for (int s = e0 + wid; s < e1; s += 4) {
    int e = eids[s];
    int src = srcs[s];
    const float* feb = fe + (size_t)e * 576 + vz;  // vector-broadcast path
    float attn = w_ws[(size_t)s * 4 + (g >> 4)] * invd;
    float ev[9];
#pragma unroll
    for (int m = 0; m < 9; m++) ev[m] = 0.f;
#pragma unroll
    for (int t = 0; t < 16; t++) {
#pragma unroll
      for (int m = 0; m < 9; m++) {
        const float4 a4 = *(const float4*)(feb + m * 64 + 4 * t);
        ev[m] += a4.x * wreg[4 * t] + a4.y * wreg[4 * t + 1] + a4.z * wreg[4 * t + 2] +
                 a4.w * wreg[4 * t + 3];
      }
    }
    const __half* vb = vh + (size_t)src * 1152 + g;
#pragma unroll
    for (int m = 0; m < 9; m++) {
      float sc = attn * ev[m];
      acc[m] += sc * __half2float(vb[m * 64]);
      acc[9 + m] += sc * __half2float(vb[m * 64 + 576]);
    }
  }
#pragma unroll
  for (int i = 0; i < 18; i++) red[wid][i * 64 + g] = acc[i];
  __syncthreads();
  for (int idx = threadIdx.x; idx < 1152; idx += 256) {
    float sv = red[0][idx] + red[1][idx] + red[2][idx] + red[3][idx];
    attn_out[(size_t)dst * 1152 + idx] = sv;
  }
}

// ---------------- K7: Wo projection + post-select + gate(a1) + residual --------------
__global__ __launch_bounds__(256) void k_wo_post2(const float* __restrict__ attn_out,
                                                  const float* __restrict__ Wo,
                                                  const float* __restrict__ xpre,
                                                  const float* __restrict__ fnodes,
                                                  const float* __restrict__ c,
                                                  const float* __restrict__ cnt,
                                                  const float* __restrict__ cutsum,
                                                  float* __restrict__ out) {
  int pm = blockIdx.y;
  int p = pm / 9, dm = deg_of(pm % 9);
  int sub = threadIdx.x >> 6, g = threadIdx.x & 63;
  int n0 = blockIdx.x * 8 + sub * 2;  // 750 blocks, 4 subs x 2 nodes
  const float* Wb = Wo + (size_t)(p * 3 + dm) * 4096;
  float wreg[64];
#pragma unroll
  for (int f = 0; f < 64; f++) wreg[f] = Wb[f * 64 + g];
  int vz = vzero();
  const float* ab = attn_out + ((size_t)n0 * 18 + pm) * 64 + vz;
  float acc[2] = {0, 0};
#pragma unroll
  for (int t = 0; t < 16; t++) {
#pragma unroll
    for (int nd = 0; nd < 2; nd++) {
      const float4 a4 = *(const float4*)(ab + (size_t)nd * 1152 + 4 * t);
      acc[nd] += a4.x * wreg[4 * t] + a4.y * wreg[4 * t + 1] + a4.z * wreg[4 * t + 2] +
                 a4.w * wreg[4 * t + 3];
    }
  }
#pragma unroll
  for (int nd = 0; nd < 2; nd++) {
    int n = n0 + nd;
    float mc = cutsum[n] / fmaxf(cnt[n], 1.f);
    size_t idx = ((size_t)n * 18 + pm) * 64 + g;
    float post = (mc < 1e-5f) ? xpre[idx] : acc[nd];
    float a1v = c[(size_t)n * 1664 + 448 + (p * 3 + dm) * 64 + g];
    out[idx] = fnodes[idx] + a1v * post;
  }
}

// ---------------- K9a: h = eqv_gelu(x_pre2 @ W1), 8 nodes/block ----------------
__global__ __launch_bounds__(256) void k_mlp1(const float* __restrict__ xp2,
                                              const float* __restrict__ W1,
                                              float* __restrict__ h) {
  int n0 = blockIdx.x * 8;  // 750 blocks
  int j = threadIdx.x;
  int vz = vzero();
  float gate[8];
  {  // pm = 0 first: its output defines the gelu gate per column
    float acc[8] = {0, 0, 0, 0, 0, 0, 0, 0};
#pragma unroll 8
    for (int f = 0; f < 64; f++) {
      float wv = W1[(size_t)f * 256 + j];
#pragma unroll
      for (int nd = 0; nd < 8; nd++)
        acc[nd] += xp2[(size_t)(n0 + nd) * 1152 + f + vz] * wv;
    }
#pragma unroll
    for (int nd = 0; nd < 8; nd++) {
      float s = acc[nd];
      float g = (fabsf(s) > 1e-4f)
                    ? 0.5f * (1.f + tanhf(0.7978845608028654f * (s + 0.044715f * s * s * s)))
                    : 0.5f;
      gate[nd] = g;
      h[(size_t)(n0 + nd) * 4608 + j] = s * g;
    }
  }
  for (int pm = 1; pm < 18; pm++) {
    int p = pm / 9, mm = pm % 9, dm = deg_of(mm);
    const float* wb = W1 + (size_t)(p * 3 + dm) * 16384;
    float acc[8] = {0, 0, 0, 0, 0, 0, 0, 0};
#pragma unroll 8
    for (int f = 0; f < 64; f++) {
      float wv = wb[(size_t)f * 256 + j];
#pragma unroll
      for (int nd = 0; nd < 8; nd++)
        acc[nd] += xp2[(size_t)(n0 + nd) * 1152 + pm * 64 + f + vz] * wv;
    }
#pragma unroll
    for (int nd = 0; nd < 8; nd++)
      h[(size_t)(n0 + nd) * 4608 + pm * 256 + j] = acc[nd] * gate[nd];
  }
}

// ---------------- K9b: out += a2 * (h @ W2), 8 nodes/block ----------------
__global__ __launch_bounds__(256) void k_mlp2(const float* __restrict__ h,
                                              const float* __restrict__ W2,
                                              const float* __restrict__ c,
                                              float* __restrict__ out) {
  int n0 = blockIdx.x * 8;  // 750 blocks
  int g = threadIdx.x & 63;
  int pr = threadIdx.x >> 6;
  int vz = vzero();
  for (int pm = pr; pm < 18; pm += 4) {
    int p = pm / 9, mm = pm % 9, dm = deg_of(mm);
    const float* wb = W2 + (size_t)(p * 3 + dm) * 16384;
    float acc[8] = {0, 0, 0, 0, 0, 0, 0, 0};
#pragma unroll 8
    for (int k = 0; k < 256; k++) {
      float wv = wb[(size_t)k * 64 + g];
#pragma unroll
      for (int nd = 0; nd < 8; nd++)
        acc[nd] += h[(size_t)(n0 + nd) * 4608 + pm * 256 + k + vz] * wv;
    }
#pragma unroll
    for (int nd = 0; nd < 8; nd++) {
      int n = n0 + nd;
      size_t idx = ((size_t)n * 18 + pm) * 64 + g;
      out[idx] += c[(size_t)n * 1664 + 1280 + (p * 3 + dm) * 64 + g] * acc[nd];
    }
  }
}

// ---------------- workspace layout (bytes) ----------------
#define OFF_C 0UL             // 39,936,000
#define OFF_XPRE 39936000UL   // 27,648,000 (reused as x_pre2)
#define OFF_QH 67584000UL     // 13,824,000 fp16 q; later attn_out (27.6M over q+k); later hbuf
#define OFF_KH 81408000UL     // 13,824,000 fp16 k
#define OFF_VH 95232000UL     // 13,824,000 fp16 v
#define OFF_SBUF 109056000UL  // 1,536,000 (dead before attention)
#define OFF_ATTN 67584000UL   // 27,648,000 fp32 (over dead q,k)
#define OFF_H 67584000UL      // 110,592,000 (over q,k,v,attn,sbuf — all dead by MLP)
#define OFF_LOGW 180000000UL  // 1,152,000
#define OFF_LMAX 181152000UL  // 96,000
#define OFF_DENOM 181248000UL // 96,000
#define OFF_CNT 181344000UL   // 24,000
#define OFF_CUTSUM 181368000UL// 24,000
#define OFF_ROWPTR 181392000UL// 24,064
#define OFF_FILLC 181416064UL // 24,000
#define OFF_EIDS 181440064UL  // 288,000
#define OFF_DSTS 181728064UL  // 288,000
#define OFF_SRCS 182016064UL  // 288,000
#define OFF_CUTS 182304064UL  // 288,000
#define WS_NEEDED 182592064UL

extern "C" void kernel_launch(void* const* d_in, const int* in_sizes, int n_in,
                              void* d_out, int out_size, void* d_ws, size_t ws_size,
                              hipStream_t stream) {
  const float* f_nodes = (const float*)d_in[0];
  const float* f_edges = (const float*)d_in[1];
  const float* f_time = (const float*)d_in[2];
  const float* cutoff = (const float*)d_in[3];
  const float* ln_s = (const float*)d_in[4];
  const float* ln_b = (const float*)d_in[5];
  const float* W_c = (const float*)d_in[6];
  const float* b_c = (const float*)d_in[7];
  const float* Wq = (const float*)d_in[8];
  const float* Wk = (const float*)d_in[9];
  const float* Wv = (const float*)d_in[10];
  const float* Wo = (const float*)d_in[11];
  const float* We_qk = (const float*)d_in[12];
  const float* We_v = (const float*)d_in[13];
  const float* W1 = (const float*)d_in[14];
  const float* W2 = (const float*)d_in[15];
  const int* src_idx = (const int*)d_in[16];
  const int* dst_idx = (const int*)d_in[17];
  float* out = (float*)d_out;
  char* ws = (char*)d_ws;
  if (ws_size < WS_NEEDED) return;  // insufficient scratch; would show as poison absmax

  float* c = (float*)(ws + OFF_C);
  float* xpre = (float*)(ws + OFF_XPRE);
  __half* qh = (__half*)(ws + OFF_QH);
  __half* kh = (__half*)(ws + OFF_KH);
  __half* vh = (__half*)(ws + OFF_VH);
  float* sbuf = (float*)(ws + OFF_SBUF);
  float* attn_out = (float*)(ws + OFF_ATTN);
  float* hbuf = (float*)(ws + OFF_H);
  float* logw = (float*)(ws + OFF_LOGW);
  unsigned* lmax = (unsigned*)(ws + OFF_LMAX);
  float* denom = (float*)(ws + OFF_DENOM);
  float* cnt = (float*)(ws + OFF_CNT);
  float* cutsum = (float*)(ws + OFF_CUTSUM);
  int* rowptr = (int*)(ws + OFF_ROWPTR);
  int* fillc = (int*)(ws + OFF_FILLC);
  int* eids = (int*)(ws + OFF_EIDS);
  int* dsts = (int*)(ws + OFF_DSTS);
  int* srcs = (int*)(ws + OFF_SRCS);
  float* cuts = (float*)(ws + OFF_CUTS);

  // zero lmax/denom/cnt/cutsum (contiguous)
  hipMemsetAsync(ws + OFF_LMAX, 0, 240000, stream);

  k_ln_t<<<1500, 256, 0, stream>>>(f_time, ln_s, ln_b, sbuf);
  k_count<<<282, 256, 0, stream>>>(dst_idx, cutoff, cnt, cutsum);
  k_cond_mm<<<750, 256, 0, stream>>>(sbuf, W_c, b_c, c);
  k_scan<<<1, 1024, 0, stream>>>(cnt, rowptr, fillc);
  k_fill<<<282, 256, 0, stream>>>(dst_idx, src_idx, cutoff, fillc, eids, dsts, srcs, cuts);
  k_lnmod<<<3000, 256, 0, stream>>>(f_nodes, c, xpre, 0, 384);

  k_qkv<<<dim3(750, 18), 192, 0, stream>>>(xpre, Wq, Wk, Wv, qh, kh, vh);

  k_flogits<<<4500, 256, 0, stream>>>(f_edges, We_qk, qh, kh, eids, dsts, srcs, logw,
                                      lmax);
  k_expw2<<<1125, 256, 0, stream>>>(logw, lmax, dsts, cuts, denom);
  k_fagg<<<6000, 256, 0, stream>>>(f_edges, We_v, vh, eids, srcs, rowptr, logw, denom,
                                   attn_out);
  k_wo_post2<<<dim3(750, 18), 256, 0, stream>>>(attn_out, Wo, xpre, f_nodes, c, cnt,
                                                cutsum, out);

  k_lnmod<<<3000, 256, 0, stream>>>(out, c, xpre, 832, 1216);  // x_pre2 (buffer reuse)
  k_mlp1<<<750, 256, 0, stream>>>(xpre, W1, hbuf);
  k_mlp2<<<750, 256, 0, stream>>>(hbuf, W2, c, out);
}

// Round 3
// 1080.262 us; speedup vs baseline: 2.0039x; 2.0039x over previous
//
#include <hip/hip_runtime.h>
#include <hip/hip_fp16.h>
#include <math.h>

// SO3 DiT layer, MI355X fp32. N=6000, E=72000, P=2, L=2, M=9, F=64, H=4, DH=16
// R3: R0-R2 lesson: any wave streaming a 2.3KB fe row via same-address loads
// (s_load x16 OR vector broadcast) is issue/latency-bound, not BW-bound.
// Fix: coalesced LDS staging of fe tiles (16 edges/block), per-edge GEMM reads
// LDS broadcasts (free) vs weight columns in VGPRs. k_edge fuses eq-GEMM +
// ev-GEMM + qk logits (eq never materialized; ev written fp16 once).
// k_fagg2 = light CSR gather over evh/vh fp16, wave per dst, write-once.
// qkv fused into one LDS-tiled kernel (xpre read once); wo_post LDS-tiled too.

#define NN 6000
#define EE 72000

__device__ __forceinline__ float wsum(float v) {
#pragma unroll
  for (int o = 32; o >= 1; o >>= 1) v += __shfl_xor(v, o, 64);
  return v;
}
__device__ __forceinline__ int deg_of(int m) { return (m == 0) ? 0 : ((m < 4) ? 1 : 2); }
// order-preserving float->uint for atomicMax-based segment max
__device__ __forceinline__ unsigned fenc(float x) {
  unsigned u = __float_as_uint(x);
  return (u & 0x80000000u) ? ~u : (u | 0x80000000u);
}
__device__ __forceinline__ float fdec(unsigned k) {
  unsigned u = (k & 0x80000000u) ? (k & 0x7fffffffu) : ~k;
  return __uint_as_float(u);
}

// ---------------- K1a: LayerNorm(T=64) + SiLU, one wave per node ----------------
__global__ __launch_bounds__(256) void k_ln_t(const float* __restrict__ ft,
                                              const float* __restrict__ lns,
                                              const float* __restrict__ lnb,
                                              float* __restrict__ sbuf) {
  int w = (blockIdx.x * 256 + threadIdx.x) >> 6;  // node, exact 6000
  int lane = threadIdx.x & 63;
  float t = ft[(size_t)w * 64 + lane];
  float mu = wsum(t) * (1.f / 64.f);
  float d = t - mu;
  float var = wsum(d * d) * (1.f / 64.f);
  float cin = d * rsqrtf(var + 1e-6f) * lns[lane] + lnb[lane];
  sbuf[(size_t)w * 64 + lane] = cin / (1.f + expf(-cin));
}

// ---------------- K1b: c = silu @ W_c + b_c  (64 -> 1664), 8 nodes/block ----------------
__global__ __launch_bounds__(256) void k_cond_mm(const float* __restrict__ sbuf,
                                                 const float* __restrict__ Wc,
                                                 const float* __restrict__ bc,
                                                 float* __restrict__ c) {
  int n0 = blockIdx.x * 8;  // 750 blocks
  for (int jj = threadIdx.x; jj < 1664; jj += 256) {
    float acc[8] = {0, 0, 0, 0, 0, 0, 0, 0};
#pragma unroll 8
    for (int k2 = 0; k2 < 64; k2++) {
      float wv = Wc[(size_t)k2 * 1664 + jj];
#pragma unroll
      for (int nd = 0; nd < 8; nd++) acc[nd] += sbuf[(size_t)(n0 + nd) * 64 + k2] * wv;
    }
    float b = bc[jj];
#pragma unroll
    for (int nd = 0; nd < 8; nd++) c[(size_t)(n0 + nd) * 1664 + jj] = acc[nd] + b;
  }
}

// ---------------- K2/K8: eqv layernorm + modulate, one wave per (n,p) ----------------
__global__ __launch_bounds__(256) void k_lnmod(const float* __restrict__ xin,
                                               const float* __restrict__ c,
                                               float* __restrict__ xout,
                                               int goff, int boff) {
  int w = (blockIdx.x * 256 + threadIdx.x) >> 6;  // (n,p) pair, exact 12000
  int lane = threadIdx.x & 63;
  int n = w >> 1, p = w & 1;
  const float* xb = xin + (size_t)w * 576 + lane;
  float x0 = xb[0], x1 = xb[64], x2 = xb[128], x3 = xb[192], x4 = xb[256];
  float x5 = xb[320], x6 = xb[384], x7 = xb[448], x8 = xb[512];
  float mu = wsum(x0) * (1.f / 64.f);
  x0 -= mu;
  float n20 = x0 * x0;
  float n21 = (x1 * x1 + x2 * x2 + x3 * x3) * (1.f / 3.f);
  float n22 = (x4 * x4 + x5 * x5 + x6 * x6 + x7 * x7 + x8 * x8) * (1.f / 5.f);
  n20 = wsum(n20) * (1.f / 64.f);
  n21 = wsum(n21) * (1.f / 64.f);
  n22 = wsum(n22) * (1.f / 64.f);
  float i0 = rsqrtf(n20 + 1e-6f), i1 = rsqrtf(n21 + 1e-6f), i2 = rsqrtf(n22 + 1e-6f);
  const float* cb = c + (size_t)n * 1664;
  float g0 = 1.f + cb[goff + p * 192 + lane];
  float g1 = 1.f + cb[goff + p * 192 + 64 + lane];
  float g2 = 1.f + cb[goff + p * 192 + 128 + lane];
  float bsh = cb[boff + lane];
  float* ob = xout + (size_t)w * 576 + lane;
  ob[0] = x0 * i0 * g0 + bsh;
  ob[64] = x1 * i1 * g1;
  ob[128] = x2 * i1 * g1;
  ob[192] = x3 * i1 * g1;
  ob[256] = x4 * i2 * g2;
  ob[320] = x5 * i2 * g2;
  ob[384] = x6 * i2 * g2;
  ob[448] = x7 * i2 * g2;
  ob[512] = x8 * i2 * g2;
}

// ---------------- CSR build: count, scan, fill ----------------
__global__ __launch_bounds__(256) void k_count(const int* __restrict__ dst_idx,
                                               const float* __restrict__ cutoff,
                                               float* __restrict__ cnt,
                                               float* __restrict__ cutsum) {
  int e = blockIdx.x * 256 + threadIdx.x;
  if (e >= EE) return;
  int d = dst_idx[e];
  unsafeAtomicAdd(cnt + d, 1.f);
  unsafeAtomicAdd(cutsum + d, cutoff[e]);
}

__global__ __launch_bounds__(1024) void k_scan(const float* __restrict__ cnt,
                                               int* __restrict__ rowptr,
                                               int* __restrict__ fillc) {
  __shared__ int part[1024];
  int t = threadIdx.x;
  int base = t * 6;  // 1024*6 = 6144 >= 6000
  int lc[6];
  int s = 0;
#pragma unroll
  for (int i = 0; i < 6; i++) {
    int idx = base + i;
    int vv = (idx < NN) ? (int)(cnt[idx] + 0.5f) : 0;
    lc[i] = s;
    s += vv;
  }
  part[t] = s;
  __syncthreads();
  for (int o = 1; o < 1024; o <<= 1) {
    int vv = (t >= o) ? part[t - o] : 0;
    __syncthreads();
    part[t] += vv;
    __syncthreads();
  }
  int ex = (t == 0) ? 0 : part[t - 1];
#pragma unroll
  for (int i = 0; i < 6; i++) {
    int idx = base + i;
    if (idx < NN) {
      int p = ex + lc[i];
      rowptr[idx] = p;
      fillc[idx] = p;
    }
  }
  if (t == 1023) rowptr[NN] = part[1023];  // == EE
}

__global__ __launch_bounds__(256) void k_fill(const int* __restrict__ dst_idx,
                                              const int* __restrict__ src_idx,
                                              const float* __restrict__ cutoff,
                                              int* __restrict__ fillc,
                                              int* __restrict__ eids,
                                              int* __restrict__ dsts,
                                              int* __restrict__ srcs,
                                              float* __restrict__ cuts) {
  int e = blockIdx.x * 256 + threadIdx.x;
  if (e >= EE) return;
  int d = dst_idx[e];
  int pos = atomicAdd(fillc + d, 1);
  eids[pos] = e;
  dsts[pos] = d;
  srcs[pos] = src_idx[e];
  cuts[pos] = cutoff[e];
}

// ---------------- K3: fused q/k/v projection, LDS-tiled, fp16 out ----------------
// grid (375, 18), 192 threads: wave = one of {q,k,v}; 16 nodes/block staged once.
__global__ __launch_bounds__(192) void k_qkv2(const float* __restrict__ xpre,
                                              const float* __restrict__ Wq,
                                              const float* __restrict__ Wk,
                                              const float* __restrict__ Wv,
                                              __half* __restrict__ qh,
                                              __half* __restrict__ kh,
                                              __half* __restrict__ vh) {
  __shared__ __align__(16) float xt[16 * 64];  // 4 KB
  int pm = blockIdx.y;
  int p = pm / 9, dm = deg_of(pm % 9);
  int n0 = blockIdx.x * 16;
  int mat = threadIdx.x >> 6;  // wave-uniform: 0=q 1=k 2=v
  int g = threadIdx.x & 63;
  for (int i = threadIdx.x; i < 1024; i += 192) {
    int r = i >> 6, f = i & 63;
    xt[i] = xpre[((size_t)(n0 + r) * 18 + pm) * 64 + f];
  }
  const float* Wsel = (mat == 0) ? Wq : ((mat == 1) ? Wk : Wv);
  const float* Wb = Wsel + (size_t)(p * 3 + dm) * 4096;
  __half* ob = (mat == 0) ? qh : ((mat == 1) ? kh : vh);
  float wreg[64];
#pragma unroll
  for (int f = 0; f < 64; f++) wreg[f] = Wb[f * 64 + g];
  __syncthreads();
  for (int r = 0; r < 16; r++) {
    float acc = 0.f;
#pragma unroll
    for (int f4 = 0; f4 < 16; f4++) {
      float4 a = *(const float4*)(xt + r * 64 + f4 * 4);  // LDS broadcast
      acc += a.x * wreg[4 * f4] + a.y * wreg[4 * f4 + 1] + a.z * wreg[4 * f4 + 2] +
             a.w * wreg[4 * f4 + 3];
    }
    ob[((size_t)(n0 + r) * 18 + pm) * 64 + g] = __float2half(acc);
  }
}

// ---------------- K4: LDS-tiled eq+ev GEMM + qk logits + segment max ----------------
// grid 4500 blocks x 256: 16 slots/block staged coalesced; wave handles 4 slots.
// eq stays in registers (never materialized); ev written fp16 once.
__global__ __launch_bounds__(256) void k_edge(const float* __restrict__ fe,
                                              const float* __restrict__ Weqk,
                                              const float* __restrict__ Wev,
                                              const __half* __restrict__ qh,
                                              const __half* __restrict__ kh,
                                              const int* __restrict__ eids,
                                              const int* __restrict__ dsts,
                                              const int* __restrict__ srcs,
                                              __half* __restrict__ evh,
                                              float* __restrict__ logw,
                                              unsigned* __restrict__ lmax) {
  __shared__ __align__(16) float ft[16 * 576];  // 36 KB
  int s0 = blockIdx.x * 16;
  int g = threadIdx.x & 63;
  int w = threadIdx.x >> 6;
  float wq[64], wv[64];
#pragma unroll
  for (int f = 0; f < 64; f++) {
    wq[f] = Weqk[f * 64 + g];
    wv[f] = Wev[f * 64 + g];
  }
  {  // coalesced stage: 16 threads per slot, 9 float4 each (256B segments)
    int sl = threadIdx.x >> 4, j = threadIdx.x & 15;
    const float* sp = fe + (size_t)eids[s0 + sl] * 576;
#pragma unroll
    for (int i = 0; i < 9; i++) {
      *(float4*)(ft + sl * 576 + i * 64 + j * 4) = *(const float4*)(sp + i * 64 + j * 4);
    }
  }
  __syncthreads();
  for (int ss = 0; ss < 4; ss++) {
    int sl = w * 4 + ss;
    int s = s0 + sl;
    float eq[9];
#pragma unroll
    for (int m = 0; m < 9; m++) {
      float eqm = 0.f, evm = 0.f;
#pragma unroll
      for (int f4 = 0; f4 < 16; f4++) {
        float4 a = *(const float4*)(ft + sl * 576 + m * 64 + f4 * 4);  // LDS broadcast
        eqm += a.x * wq[4 * f4] + a.y * wq[4 * f4 + 1] + a.z * wq[4 * f4 + 2] +
               a.w * wq[4 * f4 + 3];
        evm += a.x * wv[4 * f4] + a.y * wv[4 * f4 + 1] + a.z * wv[4 * f4 + 2] +
               a.w * wv[4 * f4 + 3];
      }
      eq[m] = eqm;
      evh[(size_t)s * 576 + m * 64 + g] = __float2half(evm);  // coalesced store
    }
    int dst = __builtin_amdgcn_readfirstlane(dsts[s]);
    int src = __builtin_amdgcn_readfirstlane(srcs[s]);
    const __half* qb = qh + (size_t)dst * 1152 + g;
    const __half* kb = kh + (size_t)src * 1152 + g;
    float lacc = 0.f;
#pragma unroll
    for (int m = 0; m < 9; m++) {
      float qk = __half2float(qb[m * 64]) * __half2float(kb[m * 64]) +
                 __half2float(qb[m * 64 + 576]) * __half2float(kb[m * 64 + 576]);
      lacc += eq[m] * qk;
    }
    lacc *= 0.05892556509887896f;  // 1/sqrt(P*M*DH)=1/sqrt(288)
    lacc += __shfl_xor(lacc, 8, 64);
    lacc += __shfl_xor(lacc, 4, 64);
    lacc += __shfl_xor(lacc, 2, 64);
    lacc += __shfl_xor(lacc, 1, 64);
    if ((g & 15) == 0) {
      int h = g >> 4;
      logw[(size_t)s * 4 + h] = lacc;
      atomicMax(lmax + (size_t)dst * 4 + h, fenc(lacc));
    }
  }
}

// ---------------- K5: w = exp(logit - lmax)*cutoff (slot order), denom sum ----------
__global__ __launch_bounds__(256) void k_expw2(float* __restrict__ logw,
                                               const unsigned* __restrict__ lmax,
                                               const int* __restrict__ dsts,
                                               const float* __restrict__ cuts,
                                               float* __restrict__ denom) {
  int t = blockIdx.x * 256 + threadIdx.x;  // exact E*4
  int s = t >> 2, h = t & 3;
  int dst = dsts[s];
  float wv = expf(logw[t] - fdec(lmax[(size_t)dst * 4 + h])) * cuts[s];
  logw[t] = wv;
  unsafeAtomicAdd(denom + (size_t)dst * 4 + h, wv);
}

// ---------------- K6: CSR gather aggregation, wave per dst, coalesced fp16 ----------
__global__ __launch_bounds__(256) void k_fagg2(const __half* __restrict__ evh,
                                               const __half* __restrict__ vh,
                                               const int* __restrict__ srcs,
                                               const int* __restrict__ rowptr,
                                               const float* __restrict__ logw,
                                               const float* __restrict__ denom,
                                               float* __restrict__ attn_out) {
  int dst = (blockIdx.x * 256 + threadIdx.x) >> 6;  // exact 6000 (1500 blocks)
  int g = threadIdx.x & 63;
  int e0 = __builtin_amdgcn_readfirstlane(rowptr[dst]);
  int e1 = __builtin_amdgcn_readfirstlane(rowptr[dst + 1]);
  float invd = 1.f / (denom[(size_t)dst * 4 + (g >> 4)] + 1e-9f);
  float acc[18];
#pragma unroll
  for (int i = 0; i < 18; i++) acc[i] = 0.f;
  for (int s = e0; s < e1; s++) {
    float attn = logw[(size_t)s * 4 + (g >> 4)] * invd;
    int src = __builtin_amdgcn_readfirstlane(srcs[s]);
    const __half* eb = evh + (size_t)s * 576 + g;
    const __half* vb = vh + (size_t)src * 1152 + g;
#pragma unroll
    for (int m = 0; m < 9; m++) {
      float sc = attn * __half2float(eb[m * 64]);
      acc[m] += sc * __half2float(vb[m * 64]);
      acc[m + 9] += sc * __half2float(vb[m * 64 + 576]);
    }
  }
  float* ob = attn_out + (size_t)dst * 1152 + g;
#pragma unroll
  for (int m = 0; m < 9; m++) {
    ob[m * 64] = acc[m];
    ob[m * 64 + 576] = acc[m + 9];
  }
}

// ---------------- K7: LDS-tiled Wo projection + post-select + gate + residual -------
__global__ __launch_bounds__(256) void k_wo_post3(const float* __restrict__ attn_out,
                                                  const float* __restrict__ Wo,
                                                  const float* __restrict__ xpre,
                                                  const float* __restrict__ fnodes,
                                                  const float* __restrict__ c,
                                                  const float* __restrict__ cnt,
                                                  const float* __restrict__ cutsum,
                                                  float* __restrict__ out) {
  __shared__ __align__(16) float xt[16 * 64];  // 4 KB
  int pm = blockIdx.y;
  int p = pm / 9, dm = deg_of(pm % 9);
  int n0 = blockIdx.x * 16;
  int g = threadIdx.x & 63, w = threadIdx.x >> 6;
  for (int i = threadIdx.x; i < 1024; i += 256) {
    int r = i >> 6, f = i & 63;
    xt[i] = attn_out[((size_t)(n0 + r) * 18 + pm) * 64 + f];
  }
  const float* Wb = Wo + (size_t)(p * 3 + dm) * 4096;
  float wreg[64];
#pragma unroll
  for (int f = 0; f < 64; f++) wreg[f] = Wb[f * 64 + g];
  __syncthreads();
  for (int i = 0; i < 4; i++) {
    int r = w * 4 + i;
    int n = n0 + r;
    float acc = 0.f;
#pragma unroll
    for (int f4 = 0; f4 < 16; f4++) {
      float4 a = *(const float4*)(xt + r * 64 + f4 * 4);
      acc += a.x * wreg[4 * f4] + a.y * wreg[4 * f4 + 1] + a.z * wreg[4 * f4 + 2] +
             a.w * wreg[4 * f4 + 3];
    }
    float mc = cutsum[n] / fmaxf(cnt[n], 1.f);
    size_t idx = ((size_t)n * 18 + pm) * 64 + g;
    float post = (mc < 1e-5f) ? xpre[idx] : acc;
    float a1v = c[(size_t)n * 1664 + 448 + (p * 3 + dm) * 64 + g];
    out[idx] = fnodes[idx] + a1v * post;
  }
}

// ---------------- K9a: h = eqv_gelu(x_pre2 @ W1), 8 nodes/block ----------------
__global__ __launch_bounds__(256) void k_mlp1(const float* __restrict__ xp2,
                                              const float* __restrict__ W1,
                                              float* __restrict__ h) {
  int n0 = blockIdx.x * 8;  // 750 blocks
  int j = threadIdx.x;
  float gate[8];
  {  // pm = 0 first: its output defines the gelu gate per column
    float acc[8] = {0, 0, 0, 0, 0, 0, 0, 0};
#pragma unroll 8
    for (int f = 0; f < 64; f++) {
      float wv = W1[(size_t)f * 256 + j];
#pragma unroll
      for (int nd = 0; nd < 8; nd++) acc[nd] += xp2[(size_t)(n0 + nd) * 1152 + f] * wv;
    }
#pragma unroll
    for (int nd = 0; nd < 8; nd++) {
      float s = acc[nd];
      float g = (fabsf(s) > 1e-4f)
                    ? 0.5f * (1.f + tanhf(0.7978845608028654f * (s + 0.044715f * s * s * s)))
                    : 0.5f;
      gate[nd] = g;
      h[(size_t)(n0 + nd) * 4608 + j] = s * g;
    }
  }
  for (int pm = 1; pm < 18; pm++) {
    int p = pm / 9, mm = pm % 9, dm = deg_of(mm);
    const float* wb = W1 + (size_t)(p * 3 + dm) * 16384;
    float acc[8] = {0, 0, 0, 0, 0, 0, 0, 0};
#pragma unroll 8
    for (int f = 0; f < 64; f++) {
      float wv = wb[(size_t)f * 256 + j];
#pragma unroll
      for (int nd = 0; nd < 8; nd++)
        acc[nd] += xp2[(size_t)(n0 + nd) * 1152 + pm * 64 + f] * wv;
    }
#pragma unroll
    for (int nd = 0; nd < 8; nd++)
      h[(size_t)(n0 + nd) * 4608 + pm * 256 + j] = acc[nd] * gate[nd];
  }
}

// ---------------- K9b: out += a2 * (h @ W2), 8 nodes/block ----------------
__global__ __launch_bounds__(256) void k_mlp2(const float* __restrict__ h,
                                              const float* __restrict__ W2,
                                              const float* __restrict__ c,
                                              float* __restrict__ out) {
  int n0 = blockIdx.x * 8;  // 750 blocks
  int g = threadIdx.x & 63;
  int pr = threadIdx.x >> 6;
  for (int pm = pr; pm < 18; pm += 4) {
    int p = pm / 9, mm = pm % 9, dm = deg_of(mm);
    const float* wb = W2 + (size_t)(p * 3 + dm) * 16384;
    float acc[8] = {0, 0, 0, 0, 0, 0, 0, 0};
#pragma unroll 8
    for (int k = 0; k < 256; k++) {
      float wv = wb[(size_t)k * 64 + g];
#pragma unroll
      for (int nd = 0; nd < 8; nd++)
        acc[nd] += h[(size_t)(n0 + nd) * 4608 + pm * 256 + k] * wv;
    }
#pragma unroll
    for (int nd = 0; nd < 8; nd++) {
      int n = n0 + nd;
      size_t idx = ((size_t)n * 18 + pm) * 64 + g;
      out[idx] += c[(size_t)n * 1664 + 1280 + (p * 3 + dm) * 64 + g] * acc[nd];
    }
  }
}

// ---------------- workspace layout (bytes) ----------------
#define OFF_C 0UL              // 39,936,000
#define OFF_XPRE 39936000UL    // 27,648,000 (reused as x_pre2)
#define OFF_QH 67584000UL      // 13,824,000 fp16 q
#define OFF_KH 81408000UL      // 13,824,000 fp16 k
#define OFF_VH 95232000UL      // 13,824,000 fp16 v
#define OFF_EVH 109056000UL    // 82,944,000 fp16 ev
#define OFF_ATTN 67584000UL    // 27,648,000 fp32 (over dead q+k after k_edge)
#define OFF_H 67584000UL       // 110,592,000 (over q,k,v,attn,ev — all dead by MLP)
#define OFF_SBUF 192000000UL   // 1,536,000
#define OFF_LOGW 193536000UL   // 1,152,000
#define OFF_LMAX 194688000UL   // 96,000
#define OFF_DENOM 194784000UL  // 96,000
#define OFF_CNT 194880000UL    // 24,000
#define OFF_CUTSUM 194904000UL // 24,000
#define OFF_ROWPTR 194928000UL // 24,064
#define OFF_FILLC 194952064UL  // 24,000
#define OFF_EIDS 194976064UL   // 288,000
#define OFF_DSTS 195264064UL   // 288,000
#define OFF_SRCS 195552064UL   // 288,000
#define OFF_CUTS 195840064UL   // 288,000
#define WS_NEEDED 196128064UL

extern "C" void kernel_launch(void* const* d_in, const int* in_sizes, int n_in,
                              void* d_out, int out_size, void* d_ws, size_t ws_size,
                              hipStream_t stream) {
  const float* f_nodes = (const float*)d_in[0];
  const float* f_edges = (const float*)d_in[1];
  const float* f_time = (const float*)d_in[2];
  const float* cutoff = (const float*)d_in[3];
  const float* ln_s = (const float*)d_in[4];
  const float* ln_b = (const float*)d_in[5];
  const float* W_c = (const float*)d_in[6];
  const float* b_c = (const float*)d_in[7];
  const float* Wq = (const float*)d_in[8];
  const float* Wk = (const float*)d_in[9];
  const float* Wv = (const float*)d_in[10];
  const float* Wo = (const float*)d_in[11];
  const float* We_qk = (const float*)d_in[12];
  const float* We_v = (const float*)d_in[13];
  const float* W1 = (const float*)d_in[14];
  const float* W2 = (const float*)d_in[15];
  const int* src_idx = (const int*)d_in[16];
  const int* dst_idx = (const int*)d_in[17];
  float* out = (float*)d_out;
  char* ws = (char*)d_ws;
  if (ws_size < WS_NEEDED) return;  // insufficient scratch; would show as poison absmax

  float* c = (float*)(ws + OFF_C);
  float* xpre = (float*)(ws + OFF_XPRE);
  __half* qh = (__half*)(ws + OFF_QH);
  __half* kh = (__half*)(ws + OFF_KH);
  __half* vh = (__half*)(ws + OFF_VH);
  __half* evh = (__half*)(ws + OFF_EVH);
  float* attn_out = (float*)(ws + OFF_ATTN);
  float* hbuf = (float*)(ws + OFF_H);
  float* sbuf = (float*)(ws + OFF_SBUF);
  float* logw = (float*)(ws + OFF_LOGW);
  unsigned* lmax = (unsigned*)(ws + OFF_LMAX);
  float* denom = (float*)(ws + OFF_DENOM);
  float* cnt = (float*)(ws + OFF_CNT);
  float* cutsum = (float*)(ws + OFF_CUTSUM);
  int* rowptr = (int*)(ws + OFF_ROWPTR);
  int* fillc = (int*)(ws + OFF_FILLC);
  int* eids = (int*)(ws + OFF_EIDS);
  int* dsts = (int*)(ws + OFF_DSTS);
  int* srcs = (int*)(ws + OFF_SRCS);
  float* cuts = (float*)(ws + OFF_CUTS);

  // zero lmax/denom/cnt/cutsum (contiguous)
  hipMemsetAsync(ws + OFF_LMAX, 0, 240000, stream);

  k_ln_t<<<1500, 256, 0, stream>>>(f_time, ln_s, ln_b, sbuf);
  k_count<<<282, 256, 0, stream>>>(dst_idx, cutoff, cnt, cutsum);
  k_cond_mm<<<750, 256, 0, stream>>>(sbuf, W_c, b_c, c);
  k_scan<<<1, 1024, 0, stream>>>(cnt, rowptr, fillc);
  k_fill<<<282, 256, 0, stream>>>(dst_idx, src_idx, cutoff, fillc, eids, dsts, srcs,
                                  cuts);
  k_lnmod<<<3000, 256, 0, stream>>>(f_nodes, c, xpre, 0, 384);

  k_qkv2<<<dim3(375, 18), 192, 0, stream>>>(xpre, Wq, Wk, Wv, qh, kh, vh);

  k_edge<<<4500, 256, 0, stream>>>(f_edges, We_qk, We_v, qh, kh, eids, dsts, srcs, evh,
                                   logw, lmax);
  k_expw2<<<1125, 256, 0, stream>>>(logw, lmax, dsts, cuts, denom);
  k_fagg2<<<1500, 256, 0, stream>>>(evh, vh, srcs, rowptr, logw, denom, attn_out);
  k_wo_post3<<<dim3(375, 18), 256, 0, stream>>>(attn_out, Wo, xpre, f_nodes, c, cnt,
                                                cutsum, out);

  k_lnmod<<<3000, 256, 0, stream>>>(out, c, xpre, 832, 1216);  // x_pre2 (buffer reuse)
  k_mlp1<<<750, 256, 0, stream>>>(xpre, W1, hbuf);
  k_mlp2<<<750, 256, 0, stream>>>(hbuf, W2, c, out);
}